// Round 1
// baseline (117.374 us; speedup 1.0000x reference)
//
#include <hip/hip_runtime.h>
#include <math.h>

// Problem constants (fixed by setup_inputs): bsz=16, sent_len=512 -> N=8192 rows,
// cont_dim D=768, mp_dim P=20. fp32 in, fp32 out.
static constexpr int D_DIM = 768;
static constexpr int NP    = 20;
static constexpr int NROWS = 8192;
static constexpr int ROWS_PER_BLOCK = 8;   // grid = 8192/8 = 1024 blocks

// Sum over each quad (lanes l, l^1, l^2, l^3) via DPP quad_perm — pure VALU,
// avoids ds_swizzle (LDS pipe) which would dominate at this reduce volume.
__device__ __forceinline__ float quad_sum(float x) {
  int a = __builtin_amdgcn_update_dpp(0, __float_as_int(x), 0xB1, 0xF, 0xF, true); // xor 1
  float y = x + __int_as_float(a);
  int b = __builtin_amdgcn_update_dpp(0, __float_as_int(y), 0x4E, 0xF, 0xF, true); // xor 2
  return y + __int_as_float(b);
}

__global__ __launch_bounds__(256) void atte_cos_kernel(
    const float* __restrict__ repres,
    const float* __restrict__ max_att,
    const float* __restrict__ weight,
    float* __restrict__ out)
{
  const int tid  = threadIdx.x;
  const int wave = tid >> 6;      // 0..3 -> perspective chunk (5 p each)
  const int lane = tid & 63;
  const int part = lane >> 4;     // 0..3
  const int sub  = lane & 15;     // 0..15
  // lane covers d = d0 + {0..3} + k*64, k=0..2  (12 elements, coalesced float4 loads:
  // per instruction 4 contiguous 256B segments)
  const int d0    = part * 192 + sub * 4;
  const int pbase = wave * 5;

  // per-wave private scratch — no __syncthreads anywhere (wave-local lgkmcnt only)
  __shared__ float sc [4][16 * 16];  // [wave][quad_id*16 + value]
  __shared__ float sc2[4][64];       // [wave][value*4 + group]

  // w^2 fragments in registers: 5 p x 3 chunks x float4 = 60 VGPRs, loaded once.
  float4 w2r[5][3];
#pragma unroll
  for (int p = 0; p < 5; ++p) {
#pragma unroll
    for (int k = 0; k < 3; ++k) {
      float4 w4 = *(const float4*)(weight + (pbase + p) * D_DIM + d0 + k * 64);
      w4.x *= w4.x; w4.y *= w4.y; w4.z *= w4.z; w4.w *= w4.w;
      w2r[p][k] = w4;
    }
  }

  const int row0 = blockIdx.x * ROWS_PER_BLOCK;
  for (int t = 0; t < ROWS_PER_BLOCK; ++t) {
    const int row = row0 + t;
    const float* rp = repres  + (size_t)row * D_DIM + d0;
    const float* mp = max_att + (size_t)row * D_DIM + d0;

    float4 r4[3], m4[3];
#pragma unroll
    for (int k = 0; k < 3; ++k) {
      r4[k] = *(const float4*)(rp + k * 64);
      m4[k] = *(const float4*)(mp + k * 64);
    }

    // acc[p*3+0]=dot partial, +1 = ||r.w||^2 partial, +2 = ||m.w||^2 partial
    float acc[16];
#pragma unroll
    for (int v = 0; v < 16; ++v) acc[v] = 0.0f;

#pragma unroll
    for (int k = 0; k < 3; ++k) {
      float rmv[4], rrv[4], mmv[4];
      const float* rv_ = (const float*)&r4[k];
      const float* mv_ = (const float*)&m4[k];
#pragma unroll
      for (int c = 0; c < 4; ++c) {
        const float rv = rv_[c], mv = mv_[c];
        rmv[c] = rv * mv; rrv[c] = rv * rv; mmv[c] = mv * mv;
      }
#pragma unroll
      for (int p = 0; p < 5; ++p) {
        const float* w = (const float*)&w2r[p][k];
#pragma unroll
        for (int c = 0; c < 4; ++c) {
          acc[p*3+0] = fmaf(rmv[c], w[c], acc[p*3+0]);
          acc[p*3+1] = fmaf(rrv[c], w[c], acc[p*3+1]);
          acc[p*3+2] = fmaf(mmv[c], w[c], acc[p*3+2]);
        }
      }
    }

    // Stage 1: DPP quad reduce (VALU). Every lane now holds its quad's sum.
#pragma unroll
    for (int v = 0; v < 15; ++v) acc[v] = quad_sum(acc[v]);
    acc[15] = 0.0f;

    // Stage 2: quad leaders (16 lanes) scatter 15 values each -> LDS (4x b128 per lane).
    if ((lane & 3) == 0) {
      const int q = lane >> 2;  // quad id 0..15
#pragma unroll
      for (int v = 0; v < 16; v += 4) {
        *(float4*)&sc[wave][q * 16 + v] =
            make_float4(acc[v], acc[v+1], acc[v+2], acc[v+3]);
      }
    }

    // Stage 3: 60 lanes each fold 4 quad-sums of one value -> sc2[value*4+group]
    {
      const int v = lane >> 2, g = lane & 3;
      if (lane < 60) {
        float p16 = sc[wave][(g*4+0)*16 + v] + sc[wave][(g*4+1)*16 + v]
                  + sc[wave][(g*4+2)*16 + v] + sc[wave][(g*4+3)*16 + v];
        sc2[wave][v * 4 + g] = p16;
      }
    }

    // Stage 4: 5 lanes finish: gather 4 group-partials per quantity, epilogue, store.
    if (lane < 5) {
      const int p = lane;
      float4 dv = *(float4*)&sc2[wave][(p*3+0)*4];
      float4 av = *(float4*)&sc2[wave][(p*3+1)*4];
      float4 bv = *(float4*)&sc2[wave][(p*3+2)*4];
      const float dot = (dv.x + dv.y) + (dv.z + dv.w);
      const float n1s = (av.x + av.y) + (av.z + av.w);
      const float n2s = (bv.x + bv.y) + (bv.z + bv.w);
      const float n1 = fmaxf(sqrtf(n1s), 1e-8f);
      const float n2 = fmaxf(sqrtf(n2s), 1e-8f);
      out[(size_t)row * NP + pbase + p] = dot / (n1 * n2);
    }
  }
}

extern "C" void kernel_launch(void* const* d_in, const int* in_sizes, int n_in,
                              void* d_out, int out_size, void* d_ws, size_t ws_size,
                              hipStream_t stream) {
  const float* repres  = (const float*)d_in[0];
  const float* max_att = (const float*)d_in[1];
  const float* weight  = (const float*)d_in[2];
  float* out = (float*)d_out;

  const int blocks = NROWS / ROWS_PER_BLOCK;  // 1024
  atte_cos_kernel<<<blocks, 256, 0, stream>>>(repres, max_att, weight, out);
}

// Round 2
// 107.095 us; speedup vs baseline: 1.0960x; 1.0960x over previous
//
#include <hip/hip_runtime.h>
#include <math.h>

// Problem constants (fixed by setup_inputs): bsz=16, sent_len=512 -> N=8192 rows,
// cont_dim D=768, mp_dim P=20. fp32 in, fp32 out.
static constexpr int D_DIM = 768;
static constexpr int NP    = 20;
static constexpr int NROWS = 8192;
static constexpr int ROWS_PER_BLOCK = 4;   // grid = 8192/4 = 2048 blocks

// One stage of a DPP reduction: x += dpp_move(x). Pure VALU — no LDS pipe.
template <int CTRL>
__device__ __forceinline__ float dpp_add(float x) {
  int t = __builtin_amdgcn_update_dpp(0, __float_as_int(x), CTRL, 0xF, 0xF, true);
  return x + __int_as_float(t);
}

// Full 64-lane sum; result valid in lane 63 only. 6 VALU instructions.
// row_shr:1/2/4/8 (0x111/0x112/0x114/0x118) then row_bcast:15 (0x142),
// row_bcast:31 (0x143). bound_ctrl=1 makes out-of-range sources contribute 0.
__device__ __forceinline__ float wave_sum63(float x) {
  x = dpp_add<0x111>(x);
  x = dpp_add<0x112>(x);
  x = dpp_add<0x114>(x);
  x = dpp_add<0x118>(x);
  x = dpp_add<0x142>(x);
  x = dpp_add<0x143>(x);
  return x;
}

__global__ __launch_bounds__(256) void atte_cos_kernel(
    const float* __restrict__ repres,
    const float* __restrict__ max_att,
    const float* __restrict__ weight,
    float* __restrict__ out)
{
  const int tid  = threadIdx.x;
  const int wave = tid >> 6;      // 0..3 -> perspective chunk (5 p each)
  const int lane = tid & 63;
  const int part = lane >> 4;     // 0..3
  const int sub  = lane & 15;     // 0..15
  // lane covers d = d0 + {0..3} + k*64, k=0..2  (12 elements; each float4 load
  // is 4 contiguous 256B segments -> fully coalesced)
  const int d0    = part * 192 + sub * 4;
  const int pbase = wave * 5;

  // w^2 fragments in registers: 5 p x 3 chunks x float4 = 60 VGPRs, loaded once
  // per block (L2/L3-warm across blocks).
  float4 w2r[5][3];
#pragma unroll
  for (int p = 0; p < 5; ++p) {
#pragma unroll
    for (int k = 0; k < 3; ++k) {
      float4 w4 = *(const float4*)(weight + (pbase + p) * D_DIM + d0 + k * 64);
      w4.x *= w4.x; w4.y *= w4.y; w4.z *= w4.z; w4.w *= w4.w;
      w2r[p][k] = w4;
    }
  }

  const int row0 = blockIdx.x * ROWS_PER_BLOCK;

  // Software pipeline: r4/m4 hold row t's data; products are extracted first so
  // the next row's loads can issue before the FMA+reduce of the current row.
  float4 r4[3], m4[3];
  {
    const float* rp = repres  + (size_t)row0 * D_DIM + d0;
    const float* mp = max_att + (size_t)row0 * D_DIM + d0;
#pragma unroll
    for (int k = 0; k < 3; ++k) {
      r4[k] = *(const float4*)(rp + k * 64);
      m4[k] = *(const float4*)(mp + k * 64);
    }
  }

  for (int t = 0; t < ROWS_PER_BLOCK; ++t) {
    const int row = row0 + t;

    // products: [k][q][c], q: 0=r*m, 1=r*r, 2=m*m  (36 VGPRs)
    float prod[3][3][4];
#pragma unroll
    for (int k = 0; k < 3; ++k) {
      const float* rv_ = (const float*)&r4[k];
      const float* mv_ = (const float*)&m4[k];
#pragma unroll
      for (int c = 0; c < 4; ++c) {
        const float rv = rv_[c], mv = mv_[c];
        prod[k][0][c] = rv * mv;
        prod[k][1][c] = rv * rv;
        prod[k][2][c] = mv * mv;
      }
    }

    // prefetch next row (overwrites r4/m4 — safe, products already extracted)
    if (t + 1 < ROWS_PER_BLOCK) {
      const float* rp = repres  + (size_t)(row + 1) * D_DIM + d0;
      const float* mp = max_att + (size_t)(row + 1) * D_DIM + d0;
#pragma unroll
      for (int k = 0; k < 3; ++k) {
        r4[k] = *(const float4*)(rp + k * 64);
        m4[k] = *(const float4*)(mp + k * 64);
      }
    }

    // acc[p*3+q]: per-lane partials for 5 perspectives x 3 quantities
    float acc[15];
#pragma unroll
    for (int v = 0; v < 15; ++v) acc[v] = 0.0f;

#pragma unroll
    for (int k = 0; k < 3; ++k) {
#pragma unroll
      for (int p = 0; p < 5; ++p) {
        const float* w = (const float*)&w2r[p][k];
#pragma unroll
        for (int c = 0; c < 4; ++c) {
          acc[p*3+0] = fmaf(prod[k][0][c], w[c], acc[p*3+0]);
          acc[p*3+1] = fmaf(prod[k][1][c], w[c], acc[p*3+1]);
          acc[p*3+2] = fmaf(prod[k][2][c], w[c], acc[p*3+2]);
        }
      }
    }

    // All-VALU 64-lane reduction; 15 independent 6-stage DPP chains interleave.
#pragma unroll
    for (int v = 0; v < 15; ++v) acc[v] = wave_sum63(acc[v]);

    // Epilogue in lane 63 only (exec-masked, ~30 VALU): 5 outputs per wave-row.
    if (lane == 63) {
#pragma unroll
      for (int p = 0; p < 5; ++p) {
        const float dot = acc[p*3+0];
        const float n1  = fmaxf(sqrtf(acc[p*3+1]), 1e-8f);
        const float n2  = fmaxf(sqrtf(acc[p*3+2]), 1e-8f);
        out[(size_t)row * NP + pbase + p] = dot / (n1 * n2);
      }
    }
  }
}

extern "C" void kernel_launch(void* const* d_in, const int* in_sizes, int n_in,
                              void* d_out, int out_size, void* d_ws, size_t ws_size,
                              hipStream_t stream) {
  const float* repres  = (const float*)d_in[0];
  const float* max_att = (const float*)d_in[1];
  const float* weight  = (const float*)d_in[2];
  float* out = (float*)d_out;

  const int blocks = NROWS / ROWS_PER_BLOCK;  // 2048
  atte_cos_kernel<<<blocks, 256, 0, stream>>>(repres, max_att, weight, out);
}